// Round 6
// baseline (155.238 us; speedup 1.0000x reference)
//
#include <hip/hip_runtime.h>

typedef __attribute__((ext_vector_type(8))) short short8;
typedef __attribute__((ext_vector_type(4))) float f32x4;
typedef __attribute__((ext_vector_type(4))) unsigned int u32x4;
typedef __attribute__((ext_vector_type(2))) unsigned long long u64x2;

static __device__ __forceinline__ unsigned int fbits(float f) {
    union { float f; unsigned int u; } v; v.f = f; return v.u;
}
static __device__ __forceinline__ float bitsf(unsigned int u) {
    union { float f; unsigned int u; } v; v.u = u; return v.f;
}
// pack two f32 -> bf16 pair in ONE VALU op (v_perm_b32 byte select; truncation --
// activations ~1e-4, threshold headroom is enormous)
static __device__ __forceinline__ unsigned int pkbf(float lo, float hi) {
    return __builtin_amdgcn_perm(fbits(hi), fbits(lo), 0x07060302u);
}
static __device__ __forceinline__ float bflo(unsigned int u) { return bitsf(u << 16); }
static __device__ __forceinline__ float bfhi(unsigned int u) { return bitsf(u & 0xFFFF0000u); }
// leaky = max(x, 0.01x): exact for both signs, 2 VALU ops
static __device__ __forceinline__ float leaky(float x) { return fmaxf(x, 0.01f * x); }
// 1/sqrt(x): v_rsq_f32 + one Newton step (~2^-23 rel err); validated r1-r5.
static __device__ __forceinline__ float rsqrt_nr(float x) {
    const float r = __builtin_amdgcn_rsqf(x);
    return r * (1.5f - (0.5f * x) * (r * r));
}

// ROUND 6: PERSISTENT GRID-STRIDE BLOCKS.
// Evidence (r3/r4/r5): achieved occupancy pins at ~11 waves/CU whenever blocks are
// fast (~5us), regardless of LDS/VGPR headroom (r5: 8 blocks/CU allowed, 2.9
// resident). Only slow (spilling) r4 blocks piled up to 23 w/CU. Diagnosis: CP
// workgroup dispatch rate bounds residency for short-lived blocks. Fix: launch
// 2048 persistent blocks (8/CU = LDS cap) that grid-stride over tiles; placement
// happens once, steady-state residency becomes resource-bound. Weight-fragment
// setup also hoists out of the per-tile loop (2048x instead of 8192x).
//
// Cross-iteration safety: all LDS traffic stays in each wave's own 64-row window;
// within it, row tid is read (phase E) and written (next iter phase A) only by
// lane tid (same-lane ds ops are in-order). Stripe-wise in-place phases (B/D) are
// guarded by the same 3 __syncthreads() per iteration as r5 (proven structure).
//
// In-place safety (r4/r5, unchanged): wave64 lockstep -> all fragment reads issue
// before any write; gate word (zr+r, i15) reader==writer lane; epilogue read g_r /
// write r' collide only if r-r'=4(q-q'), impossible for r,r' in [0,4).
//
// LDS row layout: 32 bf16 per row, k-interleaved -- u32 index c holds k=c in lo16,
// k=c+16 in hi16 (matches the HW 16x16x32 fragment layout). Row stride 9 u64
// (72 B -> max 2-way bank aliasing = free). Same k-permutation applied to the B
// (weight) fragments, so the MFMA contraction is consistent.

__global__ __launch_bounds__(256, 4) void aero_mfma(
    const float* __restrict__ vin, const float* __restrict__ win,
    const float* __restrict__ gW1, const float* __restrict__ gb1,
    const float* __restrict__ gW2, const float* __restrict__ gb2,
    const float* __restrict__ gWd1, const float* __restrict__ gbd1,
    const float* __restrict__ gWd2, const float* __restrict__ gbd2,
    const float* __restrict__ gbias,
    float* __restrict__ out, int nrows)
{
    __shared__ unsigned long long hbuf[256 * 9];  // h1 -> h2 -> z3 (in place)
    unsigned int* const h32 = (unsigned int*)hbuf;

    const int tid = threadIdx.x;
    const int i15   = tid & 15;          // n within n-tile / m within m-tile
    const int quad  = (tid >> 4) & 3;    // k-chunk selector
    const int wbase = tid & 192;         // this wave's 64-row LDS window

    // ---- hoisted per-lane B fragments (weights, k-permuted) + biases ----
    unsigned int bw2[2][4], bwd1[2][4];
    float b2v[2], bd1v[2];
    #pragma unroll
    for (int u = 0; u < 2; ++u) {
        const int n = u * 16 + i15;
        const float* p2 = gW2  + n * 32 + 4 * quad;
        const float* p3 = gWd1 + n * 32 + 4 * quad;
        #pragma unroll
        for (int j = 0; j < 4; ++j) {
            bw2[u][j]  = pkbf(p2[j], p2[j + 16]);   // bf16 pair (k=4q+j, k=4q+j+16)
            bwd1[u][j] = pkbf(p3[j], p3[j + 16]);
        }
        b2v[u]  = gb2[n];
        bd1v[u] = gbd1[n];
    }

    const int ntiles = (nrows + 255) >> 8;
    for (int tile = blockIdx.x; tile < ntiles; tile += gridDim.x) {

    int row = (tile << 8) + tid;
    if (row >= nrows) row = nrows - 1;   // benign duplicate work; keeps barriers uniform

    // ---- phase A: Gram-Schmidt + layer 1 (per-lane, lane = row) ----
    const float v0 = vin[3 * row + 0], v1 = vin[3 * row + 1], v2 = vin[3 * row + 2];
    const float w0 = win[3 * row + 0], w1 = win[3 * row + 1], w2 = win[3 * row + 2];

    const float sv  = v0 * v0 + v1 * v1 + v2 * v2;
    const float rnv = rsqrt_nr(sv);
    const float a0 = v0 * rnv, a1 = v1 * rnv, a2 = v2 * rnv;       // v_on
    const float proj = w0 * a0 + w1 * a1 + w2 * a2;
    const float o0 = w0 - proj * a0, o1 = w1 - proj * a1, o2 = w2 - proj * a2;
    const float sw  = o0 * o0 + o1 * o1 + o2 * o2;
    const float rnw = rsqrt_nr(sw);
    const float c0 = o0 * rnw, c1 = o1 * rnw, c2 = o2 * rnw;       // w_on
    const float u0 = a1 * c2 - a2 * c1;                            // u_on
    const float u1 = a2 * c0 - a0 * c2;
    const float u2 = a0 * c1 - a1 * c0;

    const float f0 = sv * rnv;     // v.v_on = |v|
    const float f1 = proj;         // w.v_on
    const float f2 = sw * rnw;     // w.w_on = |w_orth|

    float h1[32];
    #pragma unroll
    for (int j = 0; j < 32; ++j) {
        float acc = gb1[j];
        acc = fmaf(gW1[3 * j + 0], f0, acc);
        acc = fmaf(gW1[3 * j + 1], f1, acc);
        acc = fmaf(gW1[3 * j + 2], f2, acc);
        h1[j] = leaky(acc);
    }

    // pack h1 (k-interleaved) and write this lane's row
    {
        unsigned long long* dst = hbuf + tid * 9;
        #pragma unroll
        for (int c2 = 0; c2 < 8; ++c2) {
            const unsigned int lo = pkbf(h1[2 * c2],     h1[2 * c2 + 16]);
            const unsigned int hi = pkbf(h1[2 * c2 + 1], h1[2 * c2 + 17]);
            dst[c2] = (unsigned long long)lo | ((unsigned long long)hi << 32);
        }
    }

    // ---- phase B: layer 2 MFMA + FUSED leaky+gate (h2 = leaky(z2)*h1), IN PLACE ----
    __syncthreads();
    {
        const short8 bf0 = __builtin_bit_cast(short8, (u32x4){bw2[0][0], bw2[0][1], bw2[0][2], bw2[0][3]});
        const short8 bf1 = __builtin_bit_cast(short8, (u32x4){bw2[1][0], bw2[1][1], bw2[1][2], bw2[1][3]});
        const f32x4 cb0 = {b2v[0], b2v[0], b2v[0], b2v[0]};
        const f32x4 cb1 = {b2v[1], b2v[1], b2v[1], b2v[1]};
        #pragma unroll
        for (int t = 0; t < 4; ++t) {
            const int ra = wbase + 16 * t + i15;
            u64x2 av;
            av.x = hbuf[ra * 9 + 2 * quad];
            av.y = hbuf[ra * 9 + 2 * quad + 1];
            const short8 af = __builtin_bit_cast(short8, av);
            const f32x4 acc0 = __builtin_amdgcn_mfma_f32_16x16x32_bf16(af, bf0, cb0, 0, 0, 0);
            const f32x4 acc1 = __builtin_amdgcn_mfma_f32_16x16x32_bf16(af, bf1, cb1, 0, 0, 0);
            const int zr = wbase + 16 * t + 4 * quad;
            #pragma unroll
            for (int r = 0; r < 4; ++r) {
                const unsigned int g = h32[(zr + r) * 18 + i15];   // h1 pair (i15, i15+16)
                h32[(zr + r) * 18 + i15] =
                    pkbf(leaky(acc0[r]) * bflo(g), leaky(acc1[r]) * bfhi(g));
            }
        }
    }

    // ---- phase D: layer 3 as MFMA (z3 = h2 @ Wd1^T + bd1), IN PLACE ----
    __syncthreads();
    {
        const short8 bf0 = __builtin_bit_cast(short8, (u32x4){bwd1[0][0], bwd1[0][1], bwd1[0][2], bwd1[0][3]});
        const short8 bf1 = __builtin_bit_cast(short8, (u32x4){bwd1[1][0], bwd1[1][1], bwd1[1][2], bwd1[1][3]});
        const f32x4 cb0 = {bd1v[0], bd1v[0], bd1v[0], bd1v[0]};
        const f32x4 cb1 = {bd1v[1], bd1v[1], bd1v[1], bd1v[1]};
        #pragma unroll
        for (int t = 0; t < 4; ++t) {
            const int ra = wbase + 16 * t + i15;
            u64x2 av;
            av.x = hbuf[ra * 9 + 2 * quad];
            av.y = hbuf[ra * 9 + 2 * quad + 1];
            const short8 af = __builtin_bit_cast(short8, av);
            const f32x4 acc0 = __builtin_amdgcn_mfma_f32_16x16x32_bf16(af, bf0, cb0, 0, 0, 0);
            const f32x4 acc1 = __builtin_amdgcn_mfma_f32_16x16x32_bf16(af, bf1, cb1, 0, 0, 0);
            const int zr = wbase + 16 * t + 4 * quad;
            #pragma unroll
            for (int r = 0; r < 4; ++r)
                h32[(zr + r) * 18 + i15] = pkbf(acc0[r], acc1[r]);
        }
    }

    // ---- phase E: leaky(z3) per-lane, layer 4 (32->3, scalar weights), rotate, store ----
    __syncthreads();
    {
        const unsigned long long* src = hbuf + tid * 9;
        float h3[32];
        #pragma unroll
        for (int c2 = 0; c2 < 8; ++c2) {
            const unsigned long long zz = src[c2];
            const unsigned int ulo = (unsigned int)zz;
            const unsigned int uhi = (unsigned int)(zz >> 32);
            h3[2 * c2]      = leaky(bflo(ulo));
            h3[2 * c2 + 16] = leaky(bfhi(ulo));
            h3[2 * c2 + 1]  = leaky(bflo(uhi));
            h3[2 * c2 + 17] = leaky(bfhi(uhi));
        }

        float y0 = gbd2[0], y1 = gbd2[1], y2 = gbd2[2];
        #pragma unroll
        for (int k = 0; k < 32; ++k) {
            y0 = fmaf(gWd2[0 * 32 + k], h3[k], y0);
            y1 = fmaf(gWd2[1 * 32 + k], h3[k], y1);
            y2 = fmaf(gWd2[2 * 32 + k], h3[k], y2);
        }

        out[3 * row + 0] = fmaf(a0, y0, fmaf(c0, y1, fmaf(u0, y2, gbias[0])));
        out[3 * row + 1] = fmaf(a1, y0, fmaf(c1, y1, fmaf(u1, y2, gbias[1])));
        out[3 * row + 2] = fmaf(a2, y0, fmaf(c2, y1, fmaf(u2, y2, gbias[2])));
    }

    } // tile loop (no extra barrier needed: row tid is read/written only by lane tid
      // across the E -> next-A boundary; same-lane ds ops are in-order)
}

extern "C" void kernel_launch(void* const* d_in, const int* in_sizes, int n_in,
                              void* d_out, int out_size, void* d_ws, size_t ws_size,
                              hipStream_t stream) {
    const float* v    = (const float*)d_in[0];
    const float* w    = (const float*)d_in[1];
    const float* W1   = (const float*)d_in[2];
    const float* b1   = (const float*)d_in[3];
    const float* W2   = (const float*)d_in[4];
    const float* b2   = (const float*)d_in[5];
    const float* Wd1  = (const float*)d_in[6];
    const float* bd1  = (const float*)d_in[7];
    const float* Wd2  = (const float*)d_in[8];
    const float* bd2  = (const float*)d_in[9];
    const float* bias = (const float*)d_in[10];

    const int nrows = in_sizes[0] / 3;
    const int ntiles = (nrows + 255) / 256;
    const int nblocks = ntiles < 2048 ? ntiles : 2048;  // 8 blocks/CU (LDS cap), persistent
    dim3 block(256);
    dim3 grid(nblocks);
    hipLaunchKernelGGL(aero_mfma, grid, block, 0, stream,
                       v, w, W1, b1, W2, b2, Wd1, bd1, Wd2, bd2, bias,
                       (float*)d_out, nrows);
}

// Round 9
// 144.742 us; speedup vs baseline: 1.0725x; 1.0725x over previous
//
#include <hip/hip_runtime.h>

typedef __attribute__((ext_vector_type(8))) short short8;
typedef __attribute__((ext_vector_type(4))) float f32x4;
typedef __attribute__((ext_vector_type(2))) float f32x2;
typedef __attribute__((ext_vector_type(4))) unsigned int u32x4;
typedef __attribute__((ext_vector_type(2))) unsigned long long u64x2;

static __device__ __forceinline__ unsigned int fbits(float f) {
    union { float f; unsigned int u; } v; v.f = f; return v.u;
}
static __device__ __forceinline__ float bitsf(unsigned int u) {
    union { float f; unsigned int u; } v; v.u = u; return v.f;
}
// pack two f32 -> bf16 pair in ONE VALU op (v_perm_b32 byte select)
static __device__ __forceinline__ unsigned int pkbf(float lo, float hi) {
    return __builtin_amdgcn_perm(fbits(hi), fbits(lo), 0x07060302u);
}
static __device__ __forceinline__ float bflo(unsigned int u) { return bitsf(u << 16); }
static __device__ __forceinline__ float bfhi(unsigned int u) { return bitsf(u & 0xFFFF0000u); }
static __device__ __forceinline__ float leaky(float x) { return fmaxf(x, 0.01f * x); }
// 1/sqrt(x): v_rsq_f32 + one Newton step (~2^-23 rel err); validated r1-r6.
static __device__ __forceinline__ float rsqrt_nr(float x) {
    const float r = __builtin_amdgcn_rsqf(x);
    return r * (1.5f - (0.5f * x) * (r * r));
}

// packed f32 (VOP3P, CDNA: v_pk_{mul,fma,add}_f32) -- 2 FLOPs per issue slot.
// _s variants take the (wave-uniform) weight pair from an SGPR pair: exactly one
// SGPR source per VALU instruction, per ISA rules.
static __device__ __forceinline__ f32x2 pk_mul_s(f32x2 s, f32x2 v) {
    f32x2 d; asm("v_pk_mul_f32 %0, %1, %2" : "=v"(d) : "s"(s), "v"(v)); return d;
}
static __device__ __forceinline__ f32x2 pk_fma_s(f32x2 s, f32x2 v, f32x2 c) {
    f32x2 d; asm("v_pk_fma_f32 %0, %1, %2, %3" : "=v"(d) : "s"(s), "v"(v), "v"(c)); return d;
}
static __device__ __forceinline__ f32x2 pk_add_s(f32x2 s, f32x2 v) {
    f32x2 d; asm("v_pk_add_f32 %0, %1, %2" : "=v"(d) : "s"(s), "v"(v)); return d;
}
static __device__ __forceinline__ f32x2 pk_mul_v(f32x2 a, f32x2 b) {
    f32x2 d; asm("v_pk_mul_f32 %0, %1, %2" : "=v"(d) : "v"(a), "v"(b)); return d;
}
// packed leaky: pk_mul + 2 scalar max (no v_pk_max_f32 on CDNA) = 3 ops / 2 elems
static __device__ __forceinline__ f32x2 leaky2(f32x2 x, f32x2 c001) {
    const f32x2 m = pk_mul_v(x, c001);
    f32x2 r; r.x = fmaxf(x.x, m.x); r.y = fmaxf(x.y, m.y); return r;
}

// ROUND 7 kernel, resubmitted (r7: GPUAcquisitionTimeout; r8: container failed --
// both infra-side, kernel never measured):
// (a) ONE WAVE PER WORKGROUP. r6 disproved CP-dispatch limiting (persistent
// blocks: occupancy still 36%, slower); all LDS dataflow has been intra-wave
// since r4 (each wave owns its 64-row window), so the 4-wave workgroup only
// added barrier rendezvous (waves waiting for siblings at 3 syncthreads per
// ~5us block). blockDim=64 makes __syncthreads() single-wave (HW-trivial; its
// lgkmcnt(0) still provides the LDS write->read ordering we rely on). LDS
// 18432 -> 4608 B/block; residency becomes wave-slot-bound.
// (b) packed-f32 VOP3P for the two scalar matmuls: L1 pairs outputs (j,j+16) --
// exactly the LDS pack pairing, so packing cost unchanged; L4 pairs the
// k-reduction with contiguous Wd2 SGPR pairs. ~140 fewer VALU insts/lane.
// Reverted: persistent tile loop (r6, -24us).
//
// In-place hbuf safety (r4-r6, unchanged; wbase=0 now): wave64 lockstep -> all
// fragment reads issue before any write; gate word (zr+r,i15) reader==writer
// lane within a phase; epilogue read g_r / write r' collide only if r-r'=4(q-q'),
// impossible for r,r' in [0,4); __syncthreads() separates phases.
//
// LDS row layout: 32 bf16 per row, k-interleaved -- u32 index c holds k=c in
// lo16, k=c+16 in hi16. Row stride 9 u64 (72 B -> max 2-way bank aliasing =
// free). Same k-permutation applied to the B (weight) fragments.

__global__ __launch_bounds__(64, 4) void aero_mfma(
    const float* __restrict__ vin, const float* __restrict__ win,
    const float* __restrict__ gW1, const float* __restrict__ gb1,
    const float* __restrict__ gW2, const float* __restrict__ gb2,
    const float* __restrict__ gWd1, const float* __restrict__ gbd1,
    const float* __restrict__ gWd2, const float* __restrict__ gbd2,
    const float* __restrict__ gbias,
    float* __restrict__ out, int nrows)
{
    __shared__ unsigned long long hbuf[64 * 9];  // h1 -> h2 -> z3 (in place)
    unsigned int* const h32 = (unsigned int*)hbuf;

    const int tid = threadIdx.x;
    int row = blockIdx.x * 64 + tid;
    if (row >= nrows) row = nrows - 1;   // benign duplicate work

    const int i15  = tid & 15;           // n within n-tile / m within m-tile
    const int quad = (tid >> 4) & 3;     // k-chunk selector

    // ---- per-lane B fragments (weights, k-permuted) + bias for both MFMA layers ----
    unsigned int bw2[2][4], bwd1[2][4];
    float b2v[2], bd1v[2];
    #pragma unroll
    for (int u = 0; u < 2; ++u) {
        const int n = u * 16 + i15;
        const float* p2 = gW2  + n * 32 + 4 * quad;
        const float* p3 = gWd1 + n * 32 + 4 * quad;
        #pragma unroll
        for (int j = 0; j < 4; ++j) {
            bw2[u][j]  = pkbf(p2[j], p2[j + 16]);   // bf16 pair (k=4q+j, k=4q+j+16)
            bwd1[u][j] = pkbf(p3[j], p3[j + 16]);
        }
        b2v[u]  = gb2[n];
        bd1v[u] = gbd1[n];
    }

    // ---- phase A: Gram-Schmidt + layer 1 (per-lane, lane = row) ----
    const float v0 = vin[3 * row + 0], v1 = vin[3 * row + 1], v2 = vin[3 * row + 2];
    const float w0 = win[3 * row + 0], w1 = win[3 * row + 1], w2 = win[3 * row + 2];

    const float sv  = v0 * v0 + v1 * v1 + v2 * v2;
    const float rnv = rsqrt_nr(sv);
    const float a0 = v0 * rnv, a1 = v1 * rnv, a2 = v2 * rnv;       // v_on
    const float proj = w0 * a0 + w1 * a1 + w2 * a2;
    const float o0 = w0 - proj * a0, o1 = w1 - proj * a1, o2 = w2 - proj * a2;
    const float sw  = o0 * o0 + o1 * o1 + o2 * o2;
    const float rnw = rsqrt_nr(sw);
    const float c0 = o0 * rnw, c1 = o1 * rnw, c2 = o2 * rnw;       // w_on
    const float u0 = a1 * c2 - a2 * c1;                            // u_on
    const float u1 = a2 * c0 - a0 * c2;
    const float u2 = a0 * c1 - a1 * c0;

    const float f0 = sv * rnv;     // v.v_on = |v|
    const float f1 = proj;         // w.v_on
    const float f2 = sw * rnw;     // w.w_on = |w_orth|

    // L1 on packed f32: pair outputs (j, j+16) -- matches the LDS pack pairing.
    const f32x2 c001 = {0.01f, 0.01f};
    f32x2 h1p[16];
    {
        const f32x2 fv0 = {f0, f0}, fv1 = {f1, f1}, fv2 = {f2, f2};
        #pragma unroll
        for (int j = 0; j < 16; ++j) {
            const f32x2 wp0 = {gW1[3 * j + 0], gW1[3 * (j + 16) + 0]};
            const f32x2 wp1 = {gW1[3 * j + 1], gW1[3 * (j + 16) + 1]};
            const f32x2 wp2 = {gW1[3 * j + 2], gW1[3 * (j + 16) + 2]};
            const f32x2 bb  = {gb1[j], gb1[j + 16]};
            f32x2 acc = pk_mul_s(wp0, fv0);
            acc = pk_fma_s(wp1, fv1, acc);
            acc = pk_fma_s(wp2, fv2, acc);
            acc = pk_add_s(bb, acc);
            h1p[j] = leaky2(acc, c001);
        }
    }

    // pack h1 (k-interleaved) and write this lane's row
    {
        unsigned long long* dst = hbuf + tid * 9;
        #pragma unroll
        for (int c2 = 0; c2 < 8; ++c2) {
            const unsigned int lo = pkbf(h1p[2 * c2].x,     h1p[2 * c2].y);
            const unsigned int hi = pkbf(h1p[2 * c2 + 1].x, h1p[2 * c2 + 1].y);
            dst[c2] = (unsigned long long)lo | ((unsigned long long)hi << 32);
        }
    }

    // ---- phase B: layer 2 MFMA + FUSED leaky+gate (h2 = leaky(z2)*h1), IN PLACE ----
    __syncthreads();
    {
        const short8 bf0 = __builtin_bit_cast(short8, (u32x4){bw2[0][0], bw2[0][1], bw2[0][2], bw2[0][3]});
        const short8 bf1 = __builtin_bit_cast(short8, (u32x4){bw2[1][0], bw2[1][1], bw2[1][2], bw2[1][3]});
        const f32x4 cb0 = {b2v[0], b2v[0], b2v[0], b2v[0]};
        const f32x4 cb1 = {b2v[1], b2v[1], b2v[1], b2v[1]};
        #pragma unroll
        for (int t = 0; t < 4; ++t) {
            const int ra = 16 * t + i15;
            u64x2 av;
            av.x = hbuf[ra * 9 + 2 * quad];
            av.y = hbuf[ra * 9 + 2 * quad + 1];
            const short8 af = __builtin_bit_cast(short8, av);
            const f32x4 acc0 = __builtin_amdgcn_mfma_f32_16x16x32_bf16(af, bf0, cb0, 0, 0, 0);
            const f32x4 acc1 = __builtin_amdgcn_mfma_f32_16x16x32_bf16(af, bf1, cb1, 0, 0, 0);
            const int zr = 16 * t + 4 * quad;
            #pragma unroll
            for (int r = 0; r < 4; ++r) {
                const unsigned int g = h32[(zr + r) * 18 + i15];   // h1 pair (i15, i15+16)
                h32[(zr + r) * 18 + i15] =
                    pkbf(leaky(acc0[r]) * bflo(g), leaky(acc1[r]) * bfhi(g));
            }
        }
    }

    // ---- phase D: layer 3 as MFMA (z3 = h2 @ Wd1^T + bd1), IN PLACE ----
    __syncthreads();
    {
        const short8 bf0 = __builtin_bit_cast(short8, (u32x4){bwd1[0][0], bwd1[0][1], bwd1[0][2], bwd1[0][3]});
        const short8 bf1 = __builtin_bit_cast(short8, (u32x4){bwd1[1][0], bwd1[1][1], bwd1[1][2], bwd1[1][3]});
        const f32x4 cb0 = {bd1v[0], bd1v[0], bd1v[0], bd1v[0]};
        const f32x4 cb1 = {bd1v[1], bd1v[1], bd1v[1], bd1v[1]};
        #pragma unroll
        for (int t = 0; t < 4; ++t) {
            const int ra = 16 * t + i15;
            u64x2 av;
            av.x = hbuf[ra * 9 + 2 * quad];
            av.y = hbuf[ra * 9 + 2 * quad + 1];
            const short8 af = __builtin_bit_cast(short8, av);
            const f32x4 acc0 = __builtin_amdgcn_mfma_f32_16x16x32_bf16(af, bf0, cb0, 0, 0, 0);
            const f32x4 acc1 = __builtin_amdgcn_mfma_f32_16x16x32_bf16(af, bf1, cb1, 0, 0, 0);
            const int zr = 16 * t + 4 * quad;
            #pragma unroll
            for (int r = 0; r < 4; ++r)
                h32[(zr + r) * 18 + i15] = pkbf(acc0[r], acc1[r]);
        }
    }

    // ---- phase E: leaky(z3), layer 4 on packed f32 (k-pairs), rotate, store ----
    __syncthreads();
    {
        const unsigned long long* src = hbuf + tid * 9;
        f32x2 he[8], ho[8];   // he[c]=h3(2c,2c+1), ho[c]=h3(2c+16,2c+17): k-contiguous pairs
        #pragma unroll
        for (int c2 = 0; c2 < 8; ++c2) {
            const unsigned long long zz = src[c2];
            const unsigned int ulo = (unsigned int)zz;
            const unsigned int uhi = (unsigned int)(zz >> 32);
            f32x2 e; e.x = bflo(ulo); e.y = bflo(uhi);
            f32x2 o; o.x = bfhi(ulo); o.y = bfhi(uhi);
            he[c2] = leaky2(e, c001);
            ho[c2] = leaky2(o, c001);
        }

        float y[3];
        #pragma unroll
        for (int j = 0; j < 3; ++j) {
            const float* wr = gWd2 + j * 32;     // k-major: pairs are contiguous SGPR pairs
            f32x2 acc = pk_mul_s((f32x2){wr[0], wr[1]}, he[0]);
            #pragma unroll
            for (int c2 = 1; c2 < 8; ++c2)
                acc = pk_fma_s((f32x2){wr[2 * c2], wr[2 * c2 + 1]}, he[c2], acc);
            #pragma unroll
            for (int c2 = 0; c2 < 8; ++c2)
                acc = pk_fma_s((f32x2){wr[16 + 2 * c2], wr[16 + 2 * c2 + 1]}, ho[c2], acc);
            y[j] = acc.x + acc.y + gbd2[j];
        }

        out[3 * row + 0] = fmaf(a0, y[0], fmaf(c0, y[1], fmaf(u0, y[2], gbias[0])));
        out[3 * row + 1] = fmaf(a1, y[0], fmaf(c1, y[1], fmaf(u1, y[2], gbias[1])));
        out[3 * row + 2] = fmaf(a2, y[0], fmaf(c2, y[1], fmaf(u2, y[2], gbias[2])));
    }
}

extern "C" void kernel_launch(void* const* d_in, const int* in_sizes, int n_in,
                              void* d_out, int out_size, void* d_ws, size_t ws_size,
                              hipStream_t stream) {
    const float* v    = (const float*)d_in[0];
    const float* w    = (const float*)d_in[1];
    const float* W1   = (const float*)d_in[2];
    const float* b1   = (const float*)d_in[3];
    const float* W2   = (const float*)d_in[4];
    const float* b2   = (const float*)d_in[5];
    const float* Wd1  = (const float*)d_in[6];
    const float* bd1  = (const float*)d_in[7];
    const float* Wd2  = (const float*)d_in[8];
    const float* bd2  = (const float*)d_in[9];
    const float* bias = (const float*)d_in[10];

    const int nrows = in_sizes[0] / 3;
    dim3 block(64);
    dim3 grid((nrows + 63) / 64);
    hipLaunchKernelGGL(aero_mfma, grid, block, 0, stream,
                       v, w, W1, b1, W2, b2, Wd1, bd1, Wd2, bd2, bias,
                       (float*)d_out, nrows);
}

// Round 10
// 140.526 us; speedup vs baseline: 1.1047x; 1.0300x over previous
//
#include <hip/hip_runtime.h>

typedef __attribute__((ext_vector_type(8))) short short8;
typedef __attribute__((ext_vector_type(4))) float f32x4;
typedef __attribute__((ext_vector_type(2))) float f32x2;
typedef __attribute__((ext_vector_type(4))) unsigned int u32x4;

static __device__ __forceinline__ unsigned int fbits(float f) {
    union { float f; unsigned int u; } v; v.f = f; return v.u;
}
static __device__ __forceinline__ float bitsf(unsigned int u) {
    union { float f; unsigned int u; } v; v.u = u; return v.f;
}
// pack two f32 -> bf16 pair in ONE VALU op (v_perm_b32 byte select)
static __device__ __forceinline__ unsigned int pkbf(float lo, float hi) {
    return __builtin_amdgcn_perm(fbits(hi), fbits(lo), 0x07060302u);
}
static __device__ __forceinline__ float bflo(unsigned int u) { return bitsf(u << 16); }
static __device__ __forceinline__ float bfhi(unsigned int u) { return bitsf(u & 0xFFFF0000u); }
static __device__ __forceinline__ float leaky(float x) { return fmaxf(x, 0.01f * x); }
// 1/sqrt(x): v_rsq_f32 + one Newton step; validated r1-r9.
static __device__ __forceinline__ float rsqrt_nr(float x) {
    const float r = __builtin_amdgcn_rsqf(x);
    return r * (1.5f - (0.5f * x) * (r * r));
}
// packed f32 (VOP3P). _s: wave-uniform operand from SGPR pair (1 SGPR src max).
static __device__ __forceinline__ f32x2 pk_mul_s(f32x2 s, f32x2 v) {
    f32x2 d; asm("v_pk_mul_f32 %0, %1, %2" : "=v"(d) : "s"(s), "v"(v)); return d;
}
static __device__ __forceinline__ f32x2 pk_fma_s(f32x2 s, f32x2 v, f32x2 c) {
    f32x2 d; asm("v_pk_fma_f32 %0, %1, %2, %3" : "=v"(d) : "s"(s), "v"(v), "v"(c)); return d;
}
static __device__ __forceinline__ f32x2 pk_add_s(f32x2 s, f32x2 v) {
    f32x2 d; asm("v_pk_add_f32 %0, %1, %2" : "=v"(d) : "s"(s), "v"(v)); return d;
}
static __device__ __forceinline__ f32x2 pk_mul_v(f32x2 a, f32x2 b) {
    f32x2 d; asm("v_pk_mul_f32 %0, %1, %2" : "=v"(d) : "v"(a), "v"(b)); return d;
}
static __device__ __forceinline__ f32x2 pk_fma_v(f32x2 a, f32x2 b, f32x2 c) {
    f32x2 d; asm("v_pk_fma_f32 %0, %1, %2, %3" : "=v"(d) : "v"(a), "v"(b), "v"(c)); return d;
}
static __device__ __forceinline__ f32x2 leaky2(f32x2 x, f32x2 c001) {
    const f32x2 m = pk_mul_v(x, c001);
    f32x2 r; r.x = fmaxf(x.x, m.x); r.y = fmaxf(x.y, m.y); return r;
}

// ROUND 10: SWAPPED-OPERAND MFMA CHAIN -- layers 2..4 entirely in registers.
// Evidence: wall pinned 53-57us across r0/r3/r5/r9 while VALU busy fell 48->36us;
// r6 (guaranteed-resident persistent blocks) still 35% idle -> stall is a per-wave
// shared-pipe cost, prime suspect the ~64 LDS ops/lane of inter-layer round-trips.
//
// Scheme (index algebra cross-checked against the m89 C-layout rule AND the
// passing r5/r9 kernels' layouts):
//   z2^T = mfma(A=W2half, B=h1^T): lane l holds B[k(q,j)][l&15] = h1[16t+(l&15)]
//   [k in {4q+j, 4q+j+16}] -- the SAME 16B LDS read as before. C-layout gives
//   acc0[r]/acc1[r] = z2[16t+(l&15)][{4q+r, 4q+r+16}] -- IDENTICAL slot set to
//   the next B-fragment. So: leaky+gate (gate operand = the unpacked B-frag
//   itself, same lane/slots) + pkbf repack = next layer's B operand, no LDS.
//   L4: per-lane pk-dot over its 8 features + butterfly (shfl_xor 16,32) over
//   the 4 lanes sharing l&15; lane keeps tile t==quad (16t+(l&15)==tid then).
//   Rotation: lane-local GS registers, row matches. ONE __syncthreads total.
// LDS: 4x b128 write + 4x b128 read per lane (80B row stride: 16B-aligned).
// z3/h3 stay f32 (previously truncated to bf16) -> accuracy same or better.

__global__ __launch_bounds__(256, 4) void aero_mfma(
    const float* __restrict__ vin, const float* __restrict__ win,
    const float* __restrict__ gW1, const float* __restrict__ gb1,
    const float* __restrict__ gW2, const float* __restrict__ gb2,
    const float* __restrict__ gWd1, const float* __restrict__ gbd1,
    const float* __restrict__ gWd2, const float* __restrict__ gbd2,
    const float* __restrict__ gbias,
    float* __restrict__ out, int nrows)
{
    __shared__ unsigned int h1lds[256 * 20];   // 20 u32 = 80B row stride

    const int tid  = threadIdx.x;
    int row = blockIdx.x * 256 + tid;
    if (row >= nrows) row = nrows - 1;         // benign duplicate work

    const int i15   = tid & 15;
    const int quad  = (tid >> 4) & 3;
    const int wbase = tid & 192;               // wave's 64-row LDS window
    const int ko    = 4 * quad;                // k-offset of this lane's slice

    // ---- preamble: swapped-layout weight fragments + bias C-operands ----
    // A-frag (layer L, half h): lane holds W[m = h*16 + i15][k in {ko+j, ko+j+16}]
    unsigned int aW2lo[4], aW2hi[4], aWd1lo[4], aWd1hi[4];
    {
        const float* p;
        p = gW2 + i15 * 32 + ko;
        { f32x4 xa = *(const f32x4*)p, xb = *(const f32x4*)(p + 16);
          #pragma unroll
          for (int j = 0; j < 4; ++j) aW2lo[j] = pkbf(xa[j], xb[j]); }
        p = gW2 + (16 + i15) * 32 + ko;
        { f32x4 xa = *(const f32x4*)p, xb = *(const f32x4*)(p + 16);
          #pragma unroll
          for (int j = 0; j < 4; ++j) aW2hi[j] = pkbf(xa[j], xb[j]); }
        p = gWd1 + i15 * 32 + ko;
        { f32x4 xa = *(const f32x4*)p, xb = *(const f32x4*)(p + 16);
          #pragma unroll
          for (int j = 0; j < 4; ++j) aWd1lo[j] = pkbf(xa[j], xb[j]); }
        p = gWd1 + (16 + i15) * 32 + ko;
        { f32x4 xa = *(const f32x4*)p, xb = *(const f32x4*)(p + 16);
          #pragma unroll
          for (int j = 0; j < 4; ++j) aWd1hi[j] = pkbf(xa[j], xb[j]); }
    }
    // Wd2 pairs (lane-varying -> VGPR): wd2p[f][r] = {Wd2[f][ko+r], Wd2[f][ko+r+16]}
    f32x2 wd2p[3][4];
    #pragma unroll
    for (int f = 0; f < 3; ++f) {
        const f32x4 xa = *(const f32x4*)(gWd2 + f * 32 + ko);
        const f32x4 xb = *(const f32x4*)(gWd2 + f * 32 + ko + 16);
        #pragma unroll
        for (int r = 0; r < 4; ++r) { wd2p[f][r].x = xa[r]; wd2p[f][r].y = xb[r]; }
    }
    // bias C-operands: acc[r] init = b[ko+r] (C row = 4q+r)
    const f32x4 cb2lo  = *(const f32x4*)(gb2  + ko);
    const f32x4 cb2hi  = *(const f32x4*)(gb2  + 16 + ko);
    const f32x4 cbd1lo = *(const f32x4*)(gbd1 + ko);
    const f32x4 cbd1hi = *(const f32x4*)(gbd1 + 16 + ko);

    // ---- phase A: Gram-Schmidt + layer 1 (pk), pack h1 row, write LDS ----
    const float v0 = vin[3 * row + 0], v1 = vin[3 * row + 1], v2 = vin[3 * row + 2];
    const float w0 = win[3 * row + 0], w1 = win[3 * row + 1], w2 = win[3 * row + 2];

    const float sv  = v0 * v0 + v1 * v1 + v2 * v2;
    const float rnv = rsqrt_nr(sv);
    const float a0 = v0 * rnv, a1 = v1 * rnv, a2 = v2 * rnv;       // v_on
    const float proj = w0 * a0 + w1 * a1 + w2 * a2;
    const float o0 = w0 - proj * a0, o1 = w1 - proj * a1, o2 = w2 - proj * a2;
    const float sw  = o0 * o0 + o1 * o1 + o2 * o2;
    const float rnw = rsqrt_nr(sw);
    const float c0 = o0 * rnw, c1 = o1 * rnw, c2 = o2 * rnw;       // w_on
    const float u0 = a1 * c2 - a2 * c1;                            // u_on
    const float u1 = a2 * c0 - a0 * c2;
    const float u2 = a0 * c1 - a1 * c0;

    const float f0 = sv * rnv, f1 = proj, f2 = sw * rnw;

    const f32x2 c001 = {0.01f, 0.01f};
    {
        const f32x2 fv0 = {f0, f0}, fv1 = {f1, f1}, fv2 = {f2, f2};
        unsigned int hp[16];
        #pragma unroll
        for (int j = 0; j < 16; ++j) {
            const f32x2 wp0 = {gW1[3 * j + 0], gW1[3 * (j + 16) + 0]};
            const f32x2 wp1 = {gW1[3 * j + 1], gW1[3 * (j + 16) + 1]};
            const f32x2 wp2 = {gW1[3 * j + 2], gW1[3 * (j + 16) + 2]};
            const f32x2 bb  = {gb1[j], gb1[j + 16]};
            f32x2 acc = pk_mul_s(wp0, fv0);
            acc = pk_fma_s(wp1, fv1, acc);
            acc = pk_fma_s(wp2, fv2, acc);
            acc = pk_add_s(bb, acc);
            const f32x2 h = leaky2(acc, c001);
            hp[j] = pkbf(h.x, h.y);               // u32 j = (k=j lo, k=j+16 hi)
        }
        unsigned int* dst = &h1lds[tid * 20];
        *(u32x4*)(dst +  0) = (u32x4){hp[0],  hp[1],  hp[2],  hp[3]};
        *(u32x4*)(dst +  4) = (u32x4){hp[4],  hp[5],  hp[6],  hp[7]};
        *(u32x4*)(dst +  8) = (u32x4){hp[8],  hp[9],  hp[10], hp[11]};
        *(u32x4*)(dst + 12) = (u32x4){hp[12], hp[13], hp[14], hp[15]};
    }
    __syncthreads();   // the only barrier: h1 rows cross lanes within the wave

    // ---- fused layers 2..4, all in registers ----
    float y0 = 0.f, y1 = 0.f, y2 = 0.f;
    #pragma unroll
    for (int t = 0; t < 4; ++t) {
        // B-frag: h1[wbase+16t+i15][k in {ko+j, ko+j+16}]
        const u32x4 bfr = *(const u32x4*)(&h1lds[(wbase + 16 * t + i15) * 20 + ko]);
        const short8 bfrag = __builtin_bit_cast(short8, bfr);

        // layer 2 (swapped): acc0[r] = z2[row][ko+r], acc1[r] = z2[row][ko+r+16]
        const f32x4 accA = __builtin_amdgcn_mfma_f32_16x16x32_bf16(
            __builtin_bit_cast(short8, (u32x4){aW2lo[0], aW2lo[1], aW2lo[2], aW2lo[3]}),
            bfrag, cb2lo, 0, 0, 0);
        const f32x4 accB = __builtin_amdgcn_mfma_f32_16x16x32_bf16(
            __builtin_bit_cast(short8, (u32x4){aW2hi[0], aW2hi[1], aW2hi[2], aW2hi[3]}),
            bfrag, cb2hi, 0, 0, 0);

        // gate in-register: h1 values are the unpacked B-frag (same lane, same slots)
        u32x4 h2u;
        #pragma unroll
        for (int r = 0; r < 4; ++r)
            h2u[r] = pkbf(leaky(accA[r]) * bflo(bfr[r]),
                          leaky(accB[r]) * bfhi(bfr[r]));
        const short8 h2frag = __builtin_bit_cast(short8, h2u);

        // layer 3 (swapped), f32 accum
        const f32x4 accC = __builtin_amdgcn_mfma_f32_16x16x32_bf16(
            __builtin_bit_cast(short8, (u32x4){aWd1lo[0], aWd1lo[1], aWd1lo[2], aWd1lo[3]}),
            h2frag, cbd1lo, 0, 0, 0);
        const f32x4 accD = __builtin_amdgcn_mfma_f32_16x16x32_bf16(
            __builtin_bit_cast(short8, (u32x4){aWd1hi[0], aWd1hi[1], aWd1hi[2], aWd1hi[3]}),
            h2frag, cbd1hi, 0, 0, 0);

        // layer 4: per-lane packed dot over this lane's 8 features
        f32x2 h3p[4];
        #pragma unroll
        for (int r = 0; r < 4; ++r) { h3p[r].x = leaky(accC[r]); h3p[r].y = leaky(accD[r]); }
        f32x2 P0 = pk_mul_v(wd2p[0][0], h3p[0]);
        f32x2 P1 = pk_mul_v(wd2p[1][0], h3p[0]);
        f32x2 P2 = pk_mul_v(wd2p[2][0], h3p[0]);
        #pragma unroll
        for (int r = 1; r < 4; ++r) {
            P0 = pk_fma_v(wd2p[0][r], h3p[r], P0);
            P1 = pk_fma_v(wd2p[1][r], h3p[r], P1);
            P2 = pk_fma_v(wd2p[2][r], h3p[r], P2);
        }
        float s0 = P0.x + P0.y, s1 = P1.x + P1.y, s2 = P2.x + P2.y;
        // butterfly over the 4 lanes sharing i15 (q-groups partition the 32 features)
        s0 += __shfl_xor(s0, 16); s0 += __shfl_xor(s0, 32);
        s1 += __shfl_xor(s1, 16); s1 += __shfl_xor(s1, 32);
        s2 += __shfl_xor(s2, 16); s2 += __shfl_xor(s2, 32);
        // lane owns tile t == quad (then wbase+16t+i15 == tid == its GS row)
        if (quad == t) { y0 = s0; y1 = s1; y2 = s2; }
    }
    y0 += gbd2[0]; y1 += gbd2[1]; y2 += gbd2[2];

    // ---- rotate by R = [v_on | w_on | u_on], add bias, store ----
    out[3 * row + 0] = fmaf(a0, y0, fmaf(c0, y1, fmaf(u0, y2, gbias[0])));
    out[3 * row + 1] = fmaf(a1, y0, fmaf(c1, y1, fmaf(u1, y2, gbias[1])));
    out[3 * row + 2] = fmaf(a2, y0, fmaf(c2, y1, fmaf(u2, y2, gbias[2])));
}

extern "C" void kernel_launch(void* const* d_in, const int* in_sizes, int n_in,
                              void* d_out, int out_size, void* d_ws, size_t ws_size,
                              hipStream_t stream) {
    const float* v    = (const float*)d_in[0];
    const float* w    = (const float*)d_in[1];
    const float* W1   = (const float*)d_in[2];
    const float* b1   = (const float*)d_in[3];
    const float* W2   = (const float*)d_in[4];
    const float* b2   = (const float*)d_in[5];
    const float* Wd1  = (const float*)d_in[6];
    const float* bd1  = (const float*)d_in[7];
    const float* Wd2  = (const float*)d_in[8];
    const float* bd2  = (const float*)d_in[9];
    const float* bias = (const float*)d_in[10];

    const int nrows = in_sizes[0] / 3;
    dim3 block(256);
    dim3 grid((nrows + 255) / 256);
    hipLaunchKernelGGL(aero_mfma, grid, block, 0, stream,
                       v, w, W1, b1, W2, b2, Wd1, bd1, Wd2, bd2, bias,
                       (float*)d_out, nrows);
}